// Round 1
// baseline (80.585 us; speedup 1.0000x reference)
//
#include <hip/hip_runtime.h>
#include <math.h>

#define R_N   8192
#define K_TOP 32
#define TPB   1024
// exp(-10*d) = exp2(-10*log2(e)*d)
#define NEG_INVT_LOG2E (-14.426950408889634f)

__device__ __forceinline__ float fast_exp2(float x) {
#if __has_builtin(__builtin_amdgcn_exp2f)
    return __builtin_amdgcn_exp2f(x);
#else
    return exp2f(x);
#endif
}

// Bitonic sort ascending across a 32-lane half-wave. l = tid & 31.
__device__ __forceinline__ float sort32_asc(float v, int l) {
#pragma unroll
    for (int k = 2; k <= 32; k <<= 1) {
#pragma unroll
        for (int j = k >> 1; j > 0; j >>= 1) {
            float pv = __shfl_xor(v, j, 64);
            bool up = ((l & k) == 0);
            bool lower = ((l & j) == 0);
            v = (lower == up) ? fminf(v, pv) : fmaxf(v, pv);
        }
    }
    return v;
}

// Sort a bitonic 32-sequence ascending (5-stage cleanup).
__device__ __forceinline__ float merge_asc32(float v, int l) {
#pragma unroll
    for (int j = 16; j > 0; j >>= 1) {
        float pv = __shfl_xor(v, j, 64);
        v = ((l & j) == 0) ? fminf(v, pv) : fmaxf(v, pv);
    }
    return v;
}

extern "C" __global__ void __launch_bounds__(TPB)
sast_fused(const float* __restrict__ scores, const int* __restrict__ rc,
           float* __restrict__ out, int B) {
    __shared__ float sdata[R_N];                 // 32 KB: row scores
    __shared__ unsigned char cdata[R_N];         //  8 KB: ref_class (0..9)
    __shared__ float topbuf[32 * 32];            //  4 KB: tournament tree
    __shared__ float yk_lds[K_TOP];

    const int row = blockIdx.x;
    const int tid = threadIdx.x;
    const int l   = tid & 31;   // lane within 32-group (shfl_xor masks <32 stay inside)
    const int h   = tid >> 5;   // 32-group id (0..31)

    // ---- Load: coalesced float4/int4, stage to LDS, keep 8 values in regs ----
    const float4* s4 = (const float4*)(scores + (size_t)row * R_N);
    const int4*   c4 = (const int4*)rc;
    float v[8];
#pragma unroll
    for (int q = 0; q < 2; ++q) {
        int idx4 = tid + q * TPB;        // 0..2047
        float4 s = s4[idx4];
        int4   c = c4[idx4];
        int r = idx4 * 4;
        sdata[r + 0] = s.x; sdata[r + 1] = s.y;
        sdata[r + 2] = s.z; sdata[r + 3] = s.w;
        ((unsigned int*)cdata)[idx4] =
            (unsigned int)(c.x & 0xff) | ((unsigned int)(c.y & 0xff) << 8) |
            ((unsigned int)(c.z & 0xff) << 16) | ((unsigned int)(c.w & 0xff) << 24);
        v[q * 4 + 0] = s.x; v[q * 4 + 1] = s.y;
        v[q * 4 + 2] = s.z; v[q * 4 + 3] = s.w;
    }

    // ---- Phase A: per-group top-32 (ascending) via bitonic tournament ----
    float run = sort32_asc(v[0], l);
#pragma unroll
    for (int p = 1; p < 8; ++p) {
        float sv  = sort32_asc(v[p], l);
        float rev = __shfl_xor(sv, 31, 64);   // reverse within 32-group
        run = fmaxf(run, rev);                // bitonic upper half of union
        run = merge_asc32(run, l);            // -> sorted asc top-32 of union
    }

    // ---- Cross-group tree: 32 lists -> 1 (5 rounds) ----
#pragma unroll
    for (int stride = 1; stride < 32; stride <<= 1) {
        topbuf[h * 32 + l] = run;
        __syncthreads();
        if ((h & (2 * stride - 1)) == 0) {
            float pv = topbuf[(h + stride) * 32 + (l ^ 31)];
            run = fmaxf(run, pv);
            run = merge_asc32(run, l);
        }
        __syncthreads();
    }

    if (tid < 32) {                         // group 0 holds row top-32 ascending
        yk_lds[l] = run;
        out[(size_t)row * K_TOP + l] = run; // output 0: yk
    }
    __syncthreads();

    // ---- Phase B: soft_label_expectation ----
    // thread (j = tid>>5, t = tid&31): j's softmax over r = t + 32*i
    const int   j = h;
    const float y = yk_lds[j];
    float num = 0.0f, den = 0.0f;
#pragma unroll 8
    for (int i = 0; i < R_N / 32; ++i) {
        int r   = i * 32 + l;
        float s = sdata[r];
        float c = (float)cdata[r];
        float e = fast_exp2(NEG_INVT_LOG2E * fabsf(s - y));
        num = fmaf(e, c, num);
        den += e;
    }
#pragma unroll
    for (int off = 16; off > 0; off >>= 1) {
        num += __shfl_xor(num, off, 64);
        den += __shfl_xor(den, off, 64);
    }
    if (l == 0) {
        out[(size_t)B * K_TOP + (size_t)row * K_TOP + j] = num / den;  // output 1
    }
}

extern "C" void kernel_launch(void* const* d_in, const int* in_sizes, int n_in,
                              void* d_out, int out_size, void* d_ws, size_t ws_size,
                              hipStream_t stream) {
    const float* scores = (const float*)d_in[0];
    const int*   rc     = (const int*)d_in[1];
    const int R = in_sizes[1];          // 8192
    const int B = in_sizes[0] / R;      // 128
    float* out = (float*)d_out;
    hipLaunchKernelGGL(sast_fused, dim3(B), dim3(TPB), 0, stream, scores, rc, out, B);
}

// Round 2
// 77.915 us; speedup vs baseline: 1.0343x; 1.0343x over previous
//
#include <hip/hip_runtime.h>
#include <math.h>

#define R_N    8192
#define K_TOP  32
#define NSLICE 8
#define SLICE  (R_N / NSLICE)          // 1024
// exp(-10*d) = exp2(-10*log2(e)*d)
#define NEG10_LOG2E (-14.426950408889634f)

__device__ __forceinline__ float fast_exp2(float x) {
#if __has_builtin(__builtin_amdgcn_exp2f)
    return __builtin_amdgcn_exp2f(x);
#else
    return exp2f(x);
#endif
}

// ---- bitonic helpers over a 32-lane half-wave (l = tid & 31) ----

// Sort a bitonic 32-sequence ascending (5-stage cleanup).
__device__ __forceinline__ float merge_asc32(float v, int l) {
#pragma unroll
    for (int j = 16; j > 0; j >>= 1) {
        float pv = __shfl_xor(v, j, 64);
        v = ((l & j) == 0) ? fminf(v, pv) : fmaxf(v, pv);
    }
    return v;
}

// Full ascending bitonic sort of 32 values (one per lane).
__device__ __forceinline__ float sort32_asc(float v, int l) {
#pragma unroll
    for (int k = 2; k <= 32; k <<= 1) {
#pragma unroll
        for (int j = k >> 1; j > 0; j >>= 1) {
            float pv = __shfl_xor(v, j, 64);
            bool keep_min = (((l & k) == 0) == ((l & j) == 0));
            v = keep_min ? fminf(v, pv) : fmaxf(v, pv);
        }
    }
    return v;
}

// a, b each ascending-sorted 32-lists; return ascending top-32 of their union.
__device__ __forceinline__ float merge_top32(float a, float b, int l) {
    float rev = __shfl_xor(b, 31, 64);     // reverse b within 32-group
    return merge_asc32(fmaxf(a, rev), l);  // bitonic upper half -> sort
}

// ================= Kernel 1: per-row top-32 (ascending) =================
extern "C" __global__ void __launch_bounds__(1024)
k_topk(const float* __restrict__ scores, float* __restrict__ out) {
    __shared__ float topbuf[32 * 32];
    const int row = blockIdx.x;
    const int tid = threadIdx.x;
    const int l   = tid & 31;
    const int h   = tid >> 5;              // 32-group id (0..31)

    const float4* s4 = (const float4*)(scores + (size_t)row * R_N);
    float4 a = s4[tid];
    float4 b = s4[tid + 1024];
    float v[8] = {a.x, a.y, a.z, a.w, b.x, b.y, b.z, b.w};

    // 8 independent 32-wide sorts (ILP across register planes)
#pragma unroll
    for (int p = 0; p < 8; ++p) v[p] = sort32_asc(v[p], l);
    // register tree: 8 sorted lists -> top-32 of the group's 256 values
#pragma unroll
    for (int gap = 1; gap < 8; gap <<= 1)
#pragma unroll
        for (int p = 0; p < 8; p += 2 * gap)
            v[p] = merge_top32(v[p], v[p + gap], l);
    float run = v[0];

    // cross-group LDS tree: 32 lists -> 1 (5 rounds)
#pragma unroll
    for (int stride = 1; stride < 32; stride <<= 1) {
        topbuf[h * 32 + l] = run;
        __syncthreads();
        if ((h & (2 * stride - 1)) == 0) {
            float pv = topbuf[(h + stride) * 32 + (l ^ 31)];  // partner reversed
            run = merge_asc32(fmaxf(run, pv), l);
        }
        __syncthreads();
    }
    if (tid < 32) out[(size_t)row * K_TOP + l] = run;   // output 0: yk
}

// ============ Kernel 2: partial softmax expectation per (row, slice) ============
extern "C" __global__ void __launch_bounds__(256)
k_expect(const float* __restrict__ scores, const int* __restrict__ rc,
         const float* __restrict__ yk, float* __restrict__ part) {
    __shared__ float2 sc[SLICE];           // (score, class) pairs: 8 KB
    __shared__ float  yk_lds[K_TOP];
    __shared__ float  rnum[4][K_TOP], rden[4][K_TOP];

    const int row = blockIdx.x >> 3;       // NSLICE == 8
    const int sl  = blockIdx.x & (NSLICE - 1);
    const int tid = threadIdx.x;
    const int j   = tid & 31;              // which yk
    const int t   = tid >> 5;              // r-stripe (0..7)

    // stage (s, c) pairs to LDS; one float->float2x2 pack per 4 elements
    const float4* s4 = (const float4*)(scores + (size_t)row * R_N + sl * SLICE);
    const int4*   c4 = (const int4*)(rc + sl * SLICE);
    float4 s = s4[tid];
    int4   c = c4[tid];
    float4* scv = (float4*)sc;
    scv[tid * 2 + 0] = make_float4(s.x, (float)c.x, s.y, (float)c.y);
    scv[tid * 2 + 1] = make_float4(s.z, (float)c.z, s.w, (float)c.w);
    if (tid < K_TOP) yk_lds[tid] = yk[(size_t)row * K_TOP + tid];
    __syncthreads();

    const float y = yk_lds[j];
    float num = 0.0f, den = 0.0f;
    const float2* base = &sc[t * (SLICE / 8)];
#pragma unroll 8
    for (int i = 0; i < SLICE / 8; ++i) {  // 128 iters; half-wave broadcast reads
        float2 p = base[i];
        float e = fast_exp2(NEG10_LOG2E * fabsf(p.x - y));
        num = fmaf(e, p.y, num);
        den += e;
    }
    // combine the two halves of each wave (t and t^1)
    num += __shfl_xor(num, 32, 64);
    den += __shfl_xor(den, 32, 64);
    const int wv = tid >> 6;               // wave id 0..3
    if ((tid & 63) < 32) { rnum[wv][j] = num; rden[wv][j] = den; }
    __syncthreads();
    if (tid < K_TOP) {
        float n2 = rnum[0][tid] + rnum[1][tid] + rnum[2][tid] + rnum[3][tid];
        float d2 = rden[0][tid] + rden[1][tid] + rden[2][tid] + rden[3][tid];
        float* dst = part + ((size_t)row * NSLICE + sl) * (2 * K_TOP);
        dst[tid] = n2;
        dst[K_TOP + tid] = d2;
    }
}

// ================= Kernel 3: reduce slices, divide, write output 1 =================
extern "C" __global__ void __launch_bounds__(256)
k_final(const float* __restrict__ part, float* __restrict__ out, int B) {
    const int g   = blockIdx.x * 256 + threadIdx.x;   // 0 .. B*K_TOP-1
    const int row = g >> 5;
    const int j   = g & 31;
    const float* p = part + (size_t)row * NSLICE * (2 * K_TOP);
    float num = 0.0f, den = 0.0f;
#pragma unroll
    for (int s = 0; s < NSLICE; ++s) {
        num += p[s * 2 * K_TOP + j];
        den += p[s * 2 * K_TOP + K_TOP + j];
    }
    out[(size_t)B * K_TOP + g] = num / den;
}

extern "C" void kernel_launch(void* const* d_in, const int* in_sizes, int n_in,
                              void* d_out, int out_size, void* d_ws, size_t ws_size,
                              hipStream_t stream) {
    const float* scores = (const float*)d_in[0];
    const int*   rc     = (const int*)d_in[1];
    const int R = in_sizes[1];          // 8192
    const int B = in_sizes[0] / R;      // 128
    float* out  = (float*)d_out;
    float* part = (float*)d_ws;         // B * NSLICE * 64 floats = 256 KB

    hipLaunchKernelGGL(k_topk,   dim3(B),           dim3(1024), 0, stream, scores, out);
    hipLaunchKernelGGL(k_expect, dim3(B * NSLICE),  dim3(256),  0, stream, scores, rc, out, part);
    hipLaunchKernelGGL(k_final,  dim3((B * K_TOP) / 256), dim3(256), 0, stream, part, out, B);
}

// Round 3
// 75.978 us; speedup vs baseline: 1.0606x; 1.0255x over previous
//
#include <hip/hip_runtime.h>
#include <math.h>

#define R_N    8192
#define K_TOP  32
#define HALF_R 4096
// exp(-10*d) = exp2(-10*log2(e)*d)
#define NEG10_LOG2E (-14.426950408889634f)
#define CUT_DELTA   2.0f     // drop contributions below exp(-20) ~ 2e-9

__device__ __forceinline__ float fast_exp2(float x) {
#if __has_builtin(__builtin_amdgcn_exp2f)
    return __builtin_amdgcn_exp2f(x);
#else
    return exp2f(x);
#endif
}

// ---- bitonic helpers over a 32-lane half-wave (l = tid & 31) ----
__device__ __forceinline__ float merge_asc32(float v, int l) {
#pragma unroll
    for (int j = 16; j > 0; j >>= 1) {
        float pv = __shfl_xor(v, j, 64);
        v = ((l & j) == 0) ? fminf(v, pv) : fmaxf(v, pv);
    }
    return v;
}

__device__ __forceinline__ float sort32_asc(float v, int l) {
#pragma unroll
    for (int k = 2; k <= 32; k <<= 1) {
#pragma unroll
        for (int j = k >> 1; j > 0; j >>= 1) {
            float pv = __shfl_xor(v, j, 64);
            bool keep_min = (((l & k) == 0) == ((l & j) == 0));
            v = keep_min ? fminf(v, pv) : fmaxf(v, pv);
        }
    }
    return v;
}

__device__ __forceinline__ float merge_top32(float a, float b, int l) {
    float rev = __shfl_xor(b, 31, 64);
    return merge_asc32(fmaxf(a, rev), l);
}

// ================= Kernel 1: per-row top-32 (ascending) =================
extern "C" __global__ void __launch_bounds__(1024)
k_topk(const float* __restrict__ scores, float* __restrict__ out) {
    __shared__ float topbuf[32 * 32];
    const int row = blockIdx.x;
    const int tid = threadIdx.x;
    const int l   = tid & 31;
    const int h   = tid >> 5;

    const float4* s4 = (const float4*)(scores + (size_t)row * R_N);
    float4 a = s4[tid];
    float4 b = s4[tid + 1024];
    float v[8] = {a.x, a.y, a.z, a.w, b.x, b.y, b.z, b.w};

#pragma unroll
    for (int p = 0; p < 8; ++p) v[p] = sort32_asc(v[p], l);
#pragma unroll
    for (int gap = 1; gap < 8; gap <<= 1)
#pragma unroll
        for (int p = 0; p < 8; p += 2 * gap)
            v[p] = merge_top32(v[p], v[p + gap], l);
    float run = v[0];

#pragma unroll
    for (int stride = 1; stride < 32; stride <<= 1) {
        topbuf[h * 32 + l] = run;
        __syncthreads();
        if ((h & (2 * stride - 1)) == 0) {
            float pv = topbuf[(h + stride) * 32 + (l ^ 31)];
            run = merge_asc32(fmaxf(run, pv), l);
        }
        __syncthreads();
    }
    if (tid < 32) out[(size_t)row * K_TOP + l] = run;   // output 0: yk
}

// ===== Kernel 2: sparse softmax expectation, per (row, half) =====
// Only scores >= yk[0] - CUT_DELTA contribute above 2e-9; compact them to
// LDS, then each wave accumulates 4 of the 32 j's over the survivor list.
extern "C" __global__ void __launch_bounds__(512)
k_expect(const float* __restrict__ scores, const int* __restrict__ rc,
         const float* __restrict__ yk, float* __restrict__ part) {
    __shared__ float2 comp[HALF_R];            // 32 KB worst case
    __shared__ float  yk_lds[K_TOP];
    __shared__ float  rnum[8][K_TOP >> 2][4];  // wave x jgroup partials
    __shared__ unsigned int cnt;

    const int row  = blockIdx.x >> 1;
    const int half = blockIdx.x & 1;
    const int tid  = threadIdx.x;
    const int lane = tid & 63;
    const int wv   = tid >> 6;                 // 0..7

    if (tid == 0) cnt = 0;
    if (tid < K_TOP) yk_lds[tid] = yk[(size_t)row * K_TOP + tid];
    __syncthreads();
    const float cutoff = yk_lds[0] - CUT_DELTA;

    // ---- load 8 elements/thread, ballot-compact survivors into LDS ----
    const float4* s4 = (const float4*)(scores + (size_t)row * R_N + half * HALF_R);
    const int4*   c4 = (const int4*)(rc + half * HALF_R);
    float se[8], ce[8];
#pragma unroll
    for (int q = 0; q < 2; ++q) {
        float4 s = s4[tid + q * 512];
        int4   c = c4[tid + q * 512];
        se[q*4+0] = s.x; se[q*4+1] = s.y; se[q*4+2] = s.z; se[q*4+3] = s.w;
        ce[q*4+0] = (float)c.x; ce[q*4+1] = (float)c.y;
        ce[q*4+2] = (float)c.z; ce[q*4+3] = (float)c.w;
    }
#pragma unroll
    for (int e = 0; e < 8; ++e) {
        bool keep = (se[e] >= cutoff);
        unsigned long long m = __ballot(keep);
        unsigned int base = 0;
        if (lane == 0) base = atomicAdd(&cnt, (unsigned)__popcll(m));
        base = __shfl(base, 0, 64);
        if (keep) {
            unsigned int pre = (unsigned)__popcll(m & ((1ull << lane) - 1ull));
            comp[base + pre] = make_float2(se[e], ce[e]);
        }
    }
    __syncthreads();
    const int n = (int)cnt;

    // ---- each wave: 4 consecutive j's over the survivor list ----
    const int j0 = wv * 4;
    const float y0 = yk_lds[j0 + 0], y1 = yk_lds[j0 + 1];
    const float y2 = yk_lds[j0 + 2], y3 = yk_lds[j0 + 3];
    float n0 = 0, d0 = 0, n1 = 0, d1 = 0, n2 = 0, d2 = 0, n3 = 0, d3 = 0;
    for (int i = lane; i < n; i += 64) {
        float2 p = comp[i];
        float e0 = fast_exp2(NEG10_LOG2E * fabsf(p.x - y0));
        float e1 = fast_exp2(NEG10_LOG2E * fabsf(p.x - y1));
        float e2 = fast_exp2(NEG10_LOG2E * fabsf(p.x - y2));
        float e3 = fast_exp2(NEG10_LOG2E * fabsf(p.x - y3));
        n0 = fmaf(e0, p.y, n0); d0 += e0;
        n1 = fmaf(e1, p.y, n1); d1 += e1;
        n2 = fmaf(e2, p.y, n2); d2 += e2;
        n3 = fmaf(e3, p.y, n3); d3 += e3;
    }
    // butterfly over the wave for all 8 accumulators
#pragma unroll
    for (int off = 32; off > 0; off >>= 1) {
        n0 += __shfl_xor(n0, off, 64); d0 += __shfl_xor(d0, off, 64);
        n1 += __shfl_xor(n1, off, 64); d1 += __shfl_xor(d1, off, 64);
        n2 += __shfl_xor(n2, off, 64); d2 += __shfl_xor(d2, off, 64);
        n3 += __shfl_xor(n3, off, 64); d3 += __shfl_xor(d3, off, 64);
    }
    if (lane == 0) {
        rnum[wv][0][0] = n0; rnum[wv][0][1] = n1;
        rnum[wv][0][2] = n2; rnum[wv][0][3] = n3;
    }
    if (lane == 1) {
        rnum[wv][1][0] = d0; rnum[wv][1][1] = d1;
        rnum[wv][1][2] = d2; rnum[wv][1][3] = d3;
    }
    __syncthreads();
    // part layout per (row,half): [0..31]=num_j, [32..63]=den_j
    if (tid < 2 * K_TOP) {
        int which = tid >> 5;          // 0=num, 1=den
        int j     = tid & 31;
        float v = rnum[j >> 2][which][j & 3];
        part[((size_t)row * 2 + half) * (2 * K_TOP) + which * K_TOP + j] = v;
    }
}

// ======= Kernel 3: combine halves, divide, write output 1 =======
extern "C" __global__ void __launch_bounds__(256)
k_final(const float* __restrict__ part, float* __restrict__ out, int B) {
    const int g   = blockIdx.x * 256 + threadIdx.x;   // 0 .. B*K_TOP-1
    const int row = g >> 5;
    const int j   = g & 31;
    const float* p = part + (size_t)row * 2 * (2 * K_TOP);
    float num = p[j] + p[2 * K_TOP + j];
    float den = p[K_TOP + j] + p[3 * K_TOP + j];
    out[(size_t)B * K_TOP + g] = num / den;
}

extern "C" void kernel_launch(void* const* d_in, const int* in_sizes, int n_in,
                              void* d_out, int out_size, void* d_ws, size_t ws_size,
                              hipStream_t stream) {
    const float* scores = (const float*)d_in[0];
    const int*   rc     = (const int*)d_in[1];
    const int R = in_sizes[1];          // 8192
    const int B = in_sizes[0] / R;      // 128
    float* out  = (float*)d_out;
    float* part = (float*)d_ws;         // B * 2 * 64 floats = 64 KB

    hipLaunchKernelGGL(k_topk,   dim3(B),     dim3(1024), 0, stream, scores, out);
    hipLaunchKernelGGL(k_expect, dim3(B * 2), dim3(512),  0, stream, scores, rc, out, part);
    hipLaunchKernelGGL(k_final,  dim3((B * K_TOP) / 256), dim3(256), 0, stream, part, out, B);
}

// Round 4
// 72.065 us; speedup vs baseline: 1.1182x; 1.0543x over previous
//
#include <hip/hip_runtime.h>
#include <math.h>

#define R_N    8192
#define K_TOP  32
#define HALF_R 4096
// exp(-10*d) = exp2(-10*log2(e)*d)
#define NEG10_LOG2E (-14.426950408889634f)
#define CUT_DELTA   2.0f     // drop contributions below exp(-20) ~ 2e-9

__device__ __forceinline__ float fast_exp2(float x) {
#if __has_builtin(__builtin_amdgcn_exp2f)
    return __builtin_amdgcn_exp2f(x);
#else
    return exp2f(x);
#endif
}

// ---- bitonic helpers over a 32-lane half-wave (l = tid & 31) ----
__device__ __forceinline__ float merge_asc32(float v, int l) {
#pragma unroll
    for (int j = 16; j > 0; j >>= 1) {
        float pv = __shfl_xor(v, j, 64);
        v = ((l & j) == 0) ? fminf(v, pv) : fmaxf(v, pv);
    }
    return v;
}

__device__ __forceinline__ float sort32_asc(float v, int l) {
#pragma unroll
    for (int k = 2; k <= 32; k <<= 1) {
#pragma unroll
        for (int j = k >> 1; j > 0; j >>= 1) {
            float pv = __shfl_xor(v, j, 64);
            bool keep_min = (((l & k) == 0) == ((l & j) == 0));
            v = keep_min ? fminf(v, pv) : fmaxf(v, pv);
        }
    }
    return v;
}

// a, b ascending 32-lists (one elem/lane in a 32-group): ascending top-32 of union
__device__ __forceinline__ float merge_top32(float a, float b, int l) {
    float rev = __shfl_xor(b, 31, 64);
    return merge_asc32(fmaxf(a, rev), l);
}

// ========== Kernel 1: top-32 per (row, half): 256 blocks x 512 threads ==========
extern "C" __global__ void __launch_bounds__(512)
k_topk(const float* __restrict__ scores, float* __restrict__ wstop) {
    __shared__ float topbuf[16 * 32];
    const int row  = blockIdx.x >> 1;
    const int half = blockIdx.x & 1;
    const int tid  = threadIdx.x;
    const int l    = tid & 31;
    const int h    = tid >> 5;             // 32-group id (0..15)

    const float4* s4 = (const float4*)(scores + (size_t)row * R_N + half * HALF_R);
    float4 a = s4[tid];
    float4 b = s4[tid + 512];
    float v[8] = {a.x, a.y, a.z, a.w, b.x, b.y, b.z, b.w};

#pragma unroll
    for (int p = 0; p < 8; ++p) v[p] = sort32_asc(v[p], l);
#pragma unroll
    for (int gap = 1; gap < 8; gap <<= 1)
#pragma unroll
        for (int p = 0; p < 8; p += 2 * gap)
            v[p] = merge_top32(v[p], v[p + gap], l);
    float run = v[0];

#pragma unroll
    for (int stride = 1; stride < 16; stride <<= 1) {
        topbuf[h * 32 + l] = run;
        __syncthreads();
        if ((h & (2 * stride - 1)) == 0) {
            float pv = topbuf[(h + stride) * 32 + (l ^ 31)];
            run = merge_asc32(fmaxf(run, pv), l);
        }
        __syncthreads();
    }
    if (tid < 32) wstop[(size_t)blockIdx.x * K_TOP + l] = run;
}

// ========== Kernel 2: merge halves -> yk; compact; expectation; final ==========
extern "C" __global__ void __launch_bounds__(1024)
k_expect(const float* __restrict__ scores, const int* __restrict__ rc,
         const float* __restrict__ wstop, float* __restrict__ out, int B) {
    __shared__ float         cs[R_N];       // 32 KB worst-case survivors (scores)
    __shared__ unsigned char cc[R_N];       //  8 KB survivor classes
    __shared__ float         yk_m[K_TOP];
    __shared__ unsigned int  cnt;

    const int row  = blockIdx.x;
    const int tid  = threadIdx.x;
    const int lane = tid & 63;
    const int l    = tid & 31;
    const int wv   = tid >> 6;              // wave id 0..15

    if (tid == 0) cnt = 0;

    // every 32-group redundantly merges the two half top-32 lists
    float A = wstop[(size_t)row * 2 * K_TOP + l];
    float Bb = wstop[(size_t)row * 2 * K_TOP + K_TOP + l];
    float run = merge_top32(A, Bb, l);
    if (tid < K_TOP) {
        yk_m[l] = run;
        out[(size_t)row * K_TOP + l] = run;         // output 0: yk
    }
    const float cutoff = __shfl(run, 0, 64) - CUT_DELTA;  // yk[0] - delta

    // load 8 elements/thread
    const float4* s4 = (const float4*)(scores + (size_t)row * R_N);
    const int4*   c4 = (const int4*)rc;
    float se[8]; int cei[8];
#pragma unroll
    for (int q = 0; q < 2; ++q) {
        float4 s = s4[tid + q * 1024];
        int4   c = c4[tid + q * 1024];
        se[q*4+0] = s.x; se[q*4+1] = s.y; se[q*4+2] = s.z; se[q*4+3] = s.w;
        cei[q*4+0] = c.x; cei[q*4+1] = c.y; cei[q*4+2] = c.z; cei[q*4+3] = c.w;
    }
    __syncthreads();   // covers cnt=0 and yk_m before use

    // ballot-compact: all 8 ballots first (independent), one atomic per wave
    unsigned long long m[8];
    unsigned int tot = 0;
#pragma unroll
    for (int e = 0; e < 8; ++e) {
        m[e] = __ballot(se[e] >= cutoff);
        tot += (unsigned)__popcll(m[e]);
    }
    unsigned int wbase = 0;
    if (lane == 0) wbase = atomicAdd(&cnt, tot);
    wbase = __shfl(wbase, 0, 64);
    const unsigned long long lt = (1ull << lane) - 1ull;
#pragma unroll
    for (int e = 0; e < 8; ++e) {
        if (se[e] >= cutoff) {
            unsigned int idx = wbase + (unsigned)__popcll(m[e] & lt);
            cs[idx] = se[e];
            cc[idx] = (unsigned char)cei[e];
        }
        wbase += (unsigned)__popcll(m[e]);
    }
    __syncthreads();
    const int n = (int)cnt;

    // each wave owns 2 j's; accumulate over survivors
    const float y0 = yk_m[wv * 2 + 0];
    const float y1 = yk_m[wv * 2 + 1];
    float n0 = 0, d0 = 0, n1 = 0, d1 = 0;
    for (int i = lane; i < n; i += 64) {
        float s = cs[i];
        float c = (float)cc[i];
        float e0 = fast_exp2(NEG10_LOG2E * fabsf(s - y0));
        float e1 = fast_exp2(NEG10_LOG2E * fabsf(s - y1));
        n0 = fmaf(e0, c, n0); d0 += e0;
        n1 = fmaf(e1, c, n1); d1 += e1;
    }
#pragma unroll
    for (int off = 32; off > 0; off >>= 1) {
        n0 += __shfl_xor(n0, off, 64); d0 += __shfl_xor(d0, off, 64);
        n1 += __shfl_xor(n1, off, 64); d1 += __shfl_xor(d1, off, 64);
    }
    if (lane == 0) {
        float* dst = out + (size_t)B * K_TOP + (size_t)row * K_TOP + wv * 2;
        dst[0] = n0 / d0;
        dst[1] = n1 / d1;
    }
}

extern "C" void kernel_launch(void* const* d_in, const int* in_sizes, int n_in,
                              void* d_out, int out_size, void* d_ws, size_t ws_size,
                              hipStream_t stream) {
    const float* scores = (const float*)d_in[0];
    const int*   rc     = (const int*)d_in[1];
    const int R = in_sizes[1];          // 8192
    const int B = in_sizes[0] / R;      // 128
    float* out   = (float*)d_out;
    float* wstop = (float*)d_ws;        // B * 2 * 32 floats = 32 KB

    hipLaunchKernelGGL(k_topk,   dim3(B * 2), dim3(512),  0, stream, scores, wstop);
    hipLaunchKernelGGL(k_expect, dim3(B),     dim3(1024), 0, stream, scores, rc, wstop, out, B);
}

// Round 5
// 68.324 us; speedup vs baseline: 1.1794x; 1.0548x over previous
//
#include <hip/hip_runtime.h>
#include <math.h>

#define R_N    8192
#define K_TOP  32
#define HALF_R 4096
#define CAND   512
// 10*log2(e): exp(10*x) = exp2(C1*x)
#define C1     14.426950408889634f
#define NEG_BIG (-3.0e38f)

__device__ __forceinline__ float fast_exp2(float x) {
#if __has_builtin(__builtin_amdgcn_exp2f)
    return __builtin_amdgcn_exp2f(x);
#else
    return exp2f(x);
#endif
}

// ---- bitonic helpers (l = tid & 31 unless noted) ----
__device__ __forceinline__ float merge_asc32(float v, int l) {
#pragma unroll
    for (int j = 16; j > 0; j >>= 1) {
        float pv = __shfl_xor(v, j, 64);
        v = ((l & j) == 0) ? fminf(v, pv) : fmaxf(v, pv);
    }
    return v;
}

__device__ __forceinline__ float sort32_asc(float v, int l) {
#pragma unroll
    for (int k = 2; k <= 32; k <<= 1) {
#pragma unroll
        for (int j = k >> 1; j > 0; j >>= 1) {
            float pv = __shfl_xor(v, j, 64);
            bool keep_min = (((l & k) == 0) == ((l & j) == 0));
            v = keep_min ? fminf(v, pv) : fmaxf(v, pv);
        }
    }
    return v;
}

// full-wave (64-lane) ascending bitonic sort
__device__ __forceinline__ float sort64_asc(float v, int lane) {
#pragma unroll
    for (int k = 2; k <= 64; k <<= 1) {
#pragma unroll
        for (int j = k >> 1; j > 0; j >>= 1) {
            float pv = __shfl_xor(v, j, 64);
            bool keep_min = (((lane & k) == 0) == ((lane & j) == 0));
            v = keep_min ? fminf(v, pv) : fmaxf(v, pv);
        }
    }
    return v;
}

// a, b ascending 32-lists: ascending top-32 of union
__device__ __forceinline__ float merge_top32(float a, float b, int l) {
    float rev = __shfl_xor(b, 31, 64);
    return merge_asc32(fmaxf(a, rev), l);
}

// ===== Kernel 1: top-32 per (row, half) with threshold prefilter =====
extern "C" __global__ void __launch_bounds__(512)
k_topk(const float* __restrict__ scores, float* __restrict__ wstop) {
    __shared__ float    cand[CAND];
    __shared__ float    twbuf[8];
    __shared__ unsigned cnt;
    __shared__ float    topbuf[16 * 32];

    const int row  = blockIdx.x >> 1;
    const int half = blockIdx.x & 1;
    const int tid  = threadIdx.x;
    const int lane = tid & 63;
    const int l    = tid & 31;
    const int h    = tid >> 5;
    const int wv   = tid >> 6;

    const float4* s4 = (const float4*)(scores + (size_t)row * R_N + half * HALF_R);
    float4 a = s4[tid];
    float4 b = s4[tid + 512];
    float v[8] = {a.x, a.y, a.z, a.w, b.x, b.y, b.z, b.w};

    cand[tid] = NEG_BIG;                    // CAND == blockDim
    if (tid == 0) cnt = 0;

    // wave threshold: 32nd-largest of the wave's 64 thread-maxima.
    // Guarantees >=32 elements >= t_w in this wave; block t = max of the 8.
    float tmax = v[0];
#pragma unroll
    for (int e = 1; e < 8; ++e) tmax = fmaxf(tmax, v[e]);
    float srt = sort64_asc(tmax, lane);
    float t_w = __shfl(srt, 32, 64);
    if (lane == 0) twbuf[wv] = t_w;
    __syncthreads();
    float t = twbuf[0];
#pragma unroll
    for (int w = 1; w < 8; ++w) t = fmaxf(t, twbuf[w]);

    // ballot-compact survivors (v >= t); true top-32 is a subset (exact).
    unsigned long long m[8];
    unsigned tot = 0;
#pragma unroll
    for (int e = 0; e < 8; ++e) {
        m[e] = __ballot(v[e] >= t);
        tot += (unsigned)__popcll(m[e]);
    }
    unsigned wbase = 0;
    if (lane == 0) wbase = atomicAdd(&cnt, tot);
    wbase = __shfl(wbase, 0, 64);
    const unsigned long long lt = (1ull << lane) - 1ull;
#pragma unroll
    for (int e = 0; e < 8; ++e) {
        if (v[e] >= t) {
            unsigned idx = wbase + (unsigned)__popcll(m[e] & lt);
            if (idx < CAND) cand[idx] = v[e];   // ~280 expected; 512 = +14 sigma
        }
        wbase += (unsigned)__popcll(m[e]);
    }
    __syncthreads();

    // top-32 of the (padded) 512 candidates: 16 group-sorts + LDS merge tree
    float run = sort32_asc(cand[tid], l);
#pragma unroll
    for (int stride = 1; stride < 16; stride <<= 1) {
        topbuf[h * 32 + l] = run;
        __syncthreads();
        if ((h & (2 * stride - 1)) == 0) {
            float pv = topbuf[(h + stride) * 32 + (l ^ 31)];
            run = merge_asc32(fmaxf(run, pv), l);
        }
        __syncthreads();
    }
    if (tid < 32) wstop[(size_t)blockIdx.x * K_TOP + l] = run;
}

// ===== Kernel 2: separable-exp expectation (exact), one block per row =====
extern "C" __global__ void __launch_bounds__(1024)
k_expect(const float* __restrict__ scores, const int* __restrict__ rc,
         const float* __restrict__ wstop, float* __restrict__ out, int B) {
    __shared__ float    dsS[32], dsC[32];   // elements strictly > y0: at most 31
    __shared__ unsigned dcnt;
    __shared__ float    pbuf[16 * 2];

    const int row  = blockIdx.x;
    const int tid  = threadIdx.x;
    const int lane = tid & 63;
    const int l    = tid & 31;
    const int wv   = tid >> 6;              // 0..15

    if (tid == 0) dcnt = 0;

    // merge the two half top-32 lists -> global yk (each 32-group redundantly)
    float A  = wstop[(size_t)row * 2 * K_TOP + l];
    float Bv = wstop[(size_t)row * 2 * K_TOP + K_TOP + l];
    float yk = merge_top32(A, Bv, l);
    if (tid < 32) out[(size_t)row * K_TOP + l] = yk;   // output 0
    const float y0 = __shfl(yk, 0, 64);

    const float4* s4 = (const float4*)(scores + (size_t)row * R_N);
    const int4*   c4 = (const int4*)rc;
    float4 sa = s4[tid], sb = s4[tid + 1024];
    int4   ca = c4[tid], cb = c4[tid + 1024];
    float se[8] = {sa.x, sa.y, sa.z, sa.w, sb.x, sb.y, sb.z, sb.w};
    float ce[8] = {(float)ca.x, (float)ca.y, (float)ca.z, (float)ca.w,
                   (float)cb.x, (float)cb.y, (float)cb.z, (float)cb.w};
    __syncthreads();                         // dcnt=0 visible before atomics

    // s <= y0 <= all y_j  =>  exp(-10|s-y_j|) = exp2(-C1*y_j) * exp2(C1*s):
    // accumulate shared P, Pc; scatter the <=31 strictly-greater elements.
    float P = 0.f, Pc = 0.f;
#pragma unroll
    for (int e = 0; e < 8; ++e) {
        if (se[e] <= y0) {
            float ex = fast_exp2(C1 * se[e]);
            P += ex;
            Pc = fmaf(ce[e], ex, Pc);
        } else {
            unsigned idx = atomicAdd(&dcnt, 1u);
            dsS[idx] = se[e];
            dsC[idx] = ce[e];
        }
    }
#pragma unroll
    for (int off = 32; off > 0; off >>= 1) {
        P  += __shfl_xor(P,  off, 64);
        Pc += __shfl_xor(Pc, off, 64);
    }
    if (lane == 0) { pbuf[wv * 2] = P; pbuf[wv * 2 + 1] = Pc; }
    __syncthreads();
    float Pt = 0.f, Pct = 0.f;
#pragma unroll
    for (int w = 0; w < 16; ++w) { Pt += pbuf[w * 2]; Pct += pbuf[w * 2 + 1]; }
    const int nD = (int)dcnt;

    // wave wv owns j = 2wv, 2wv+1; direct part over the <=31 held-out elements
    const float yj0 = __shfl(yk, 2 * wv,     64);
    const float yj1 = __shfl(yk, 2 * wv + 1, 64);
    float n0 = 0.f, d0 = 0.f, n1 = 0.f, d1 = 0.f;
    if (lane < nD) {
        float s = dsS[lane], c = dsC[lane];
        float e0 = fast_exp2(-C1 * fabsf(s - yj0));
        float e1 = fast_exp2(-C1 * fabsf(s - yj1));
        d0 = e0; n0 = c * e0;
        d1 = e1; n1 = c * e1;
    }
#pragma unroll
    for (int off = 32; off > 0; off >>= 1) {
        n0 += __shfl_xor(n0, off, 64); d0 += __shfl_xor(d0, off, 64);
        n1 += __shfl_xor(n1, off, 64); d1 += __shfl_xor(d1, off, 64);
    }
    if (lane == 0) {
        float e0 = fast_exp2(-C1 * yj0);
        float e1 = fast_exp2(-C1 * yj1);
        float* dst = out + (size_t)B * K_TOP + (size_t)row * K_TOP + 2 * wv;
        dst[0] = fmaf(Pct, e0, n0) / fmaf(Pt, e0, d0);
        dst[1] = fmaf(Pct, e1, n1) / fmaf(Pt, e1, d1);
    }
}

extern "C" void kernel_launch(void* const* d_in, const int* in_sizes, int n_in,
                              void* d_out, int out_size, void* d_ws, size_t ws_size,
                              hipStream_t stream) {
    const float* scores = (const float*)d_in[0];
    const int*   rc     = (const int*)d_in[1];
    const int R = in_sizes[1];          // 8192
    const int B = in_sizes[0] / R;      // 128
    float* out   = (float*)d_out;
    float* wstop = (float*)d_ws;        // B * 2 * 32 floats = 32 KB

    hipLaunchKernelGGL(k_topk,   dim3(B * 2), dim3(512),  0, stream, scores, wstop);
    hipLaunchKernelGGL(k_expect, dim3(B),     dim3(1024), 0, stream, scores, rc, wstop, out, B);
}

// Round 6
// 66.857 us; speedup vs baseline: 1.2053x; 1.0219x over previous
//
#include <hip/hip_runtime.h>
#include <math.h>

#define R_N    8192
#define K_TOP  32
#define CAND   1024
// 10*log2(e): exp(10*x) = exp2(C1*x)
#define C1     14.426950408889634f
#define NEG_BIG (-3.0e38f)

__device__ __forceinline__ float fast_exp2(float x) {
#if __has_builtin(__builtin_amdgcn_exp2f)
    return __builtin_amdgcn_exp2f(x);
#else
    return exp2f(x);
#endif
}

// ---- bitonic helpers (l = tid & 31 unless noted) ----
__device__ __forceinline__ float merge_asc32(float v, int l) {
#pragma unroll
    for (int j = 16; j > 0; j >>= 1) {
        float pv = __shfl_xor(v, j, 64);
        v = ((l & j) == 0) ? fminf(v, pv) : fmaxf(v, pv);
    }
    return v;
}

__device__ __forceinline__ float sort32_asc(float v, int l) {
#pragma unroll
    for (int k = 2; k <= 32; k <<= 1) {
#pragma unroll
        for (int j = k >> 1; j > 0; j >>= 1) {
            float pv = __shfl_xor(v, j, 64);
            bool keep_min = (((l & k) == 0) == ((l & j) == 0));
            v = keep_min ? fminf(v, pv) : fmaxf(v, pv);
        }
    }
    return v;
}

// full-wave (64-lane) ascending bitonic sort
__device__ __forceinline__ float sort64_asc(float v, int lane) {
#pragma unroll
    for (int k = 2; k <= 64; k <<= 1) {
#pragma unroll
        for (int j = k >> 1; j > 0; j >>= 1) {
            float pv = __shfl_xor(v, j, 64);
            bool keep_min = (((lane & k) == 0) == ((lane & j) == 0));
            v = keep_min ? fminf(v, pv) : fmaxf(v, pv);
        }
    }
    return v;
}

// ===== Fused kernel: one block per row =====
// Phase 1: threshold-prefiltered exact top-32.
// Phase 2: separable-exp softmax expectation from registers (exact).
extern "C" __global__ void __launch_bounds__(1024)
k_fused(const float* __restrict__ scores, const int* __restrict__ rc,
        float* __restrict__ out, int B) {
    __shared__ float    cand[CAND];      // 4 KB survivor scores
    __shared__ float    topbuf[32 * 32]; // 4 KB merge tree
    __shared__ float    twbuf[16];
    __shared__ float    yk_lds[K_TOP];
    __shared__ float    pbuf[16 * 2];
    __shared__ float    dsS[32], dsC[32]; // elements strictly > y0: at most 31
    __shared__ unsigned cnt, dcnt;

    const int row  = blockIdx.x;
    const int tid  = threadIdx.x;
    const int lane = tid & 63;
    const int l    = tid & 31;
    const int h    = tid >> 5;           // 32-group id (0..31)
    const int wv   = tid >> 6;           // wave id (0..15)

    // ---- load 8 scores + 8 classes per thread; hold in registers ----
    const float4* s4 = (const float4*)(scores + (size_t)row * R_N);
    const int4*   c4 = (const int4*)rc;
    float4 sa = s4[tid], sb = s4[tid + 1024];
    int4   ca = c4[tid], cb = c4[tid + 1024];
    float se[8] = {sa.x, sa.y, sa.z, sa.w, sb.x, sb.y, sb.z, sb.w};
    float ce[8] = {(float)ca.x, (float)ca.y, (float)ca.z, (float)ca.w,
                   (float)cb.x, (float)cb.y, (float)cb.z, (float)cb.w};

    cand[tid & (CAND - 1)] = NEG_BIG;    // CAND == blockDim
    if (tid == 0) { cnt = 0; dcnt = 0; }

    // ---- wave threshold: 32nd-largest of the wave's 64 thread-maxima ----
    // The achieving wave proves >=32 elements >= t, so true top-32 survives.
    float tmax = se[0];
#pragma unroll
    for (int e = 1; e < 8; ++e) tmax = fmaxf(tmax, se[e]);
    float srt = sort64_asc(tmax, lane);
    float t_w = __shfl(srt, 32, 64);
    if (lane == 0) twbuf[wv] = t_w;
    __syncthreads();
    float t = twbuf[0];
#pragma unroll
    for (int w = 1; w < 16; ++w) t = fmaxf(t, twbuf[w]);

    // ---- ballot-compact survivors into cand ----
    unsigned long long m[8];
    unsigned tot = 0;
#pragma unroll
    for (int e = 0; e < 8; ++e) {
        m[e] = __ballot(se[e] >= t);
        tot += (unsigned)__popcll(m[e]);
    }
    unsigned wbase = 0;
    if (lane == 0) wbase = atomicAdd(&cnt, tot);
    wbase = __shfl(wbase, 0, 64);
    const unsigned long long ltm = (1ull << lane) - 1ull;
#pragma unroll
    for (int e = 0; e < 8; ++e) {
        if (se[e] >= t) {
            unsigned idx = wbase + (unsigned)__popcll(m[e] & ltm);
            if (idx < CAND) cand[idx] = se[e];  // ~475 expected of 8192
        }
        wbase += (unsigned)__popcll(m[e]);
    }
    __syncthreads();

    // ---- top-32 of 1024 candidates: 32 group-sorts + 5-round LDS tree ----
    float run = sort32_asc(cand[tid], l);
#pragma unroll
    for (int stride = 1; stride < 32; stride <<= 1) {
        topbuf[h * 32 + l] = run;
        __syncthreads();
        if ((h & (2 * stride - 1)) == 0) {
            float pv = topbuf[(h + stride) * 32 + (l ^ 31)];
            run = merge_asc32(fmaxf(run, pv), l);
        }
        __syncthreads();
    }
    if (tid < 32) {
        yk_lds[l] = run;
        out[(size_t)row * K_TOP + l] = run;     // output 0: yk
    }
    __syncthreads();
    const float y0 = yk_lds[0];

    // ---- separable exp: s <= y0 <= y_j => exp(-10|s-y_j|) = e^{-10 y_j} e^{10 s}
    float P = 0.f, Pc = 0.f;
#pragma unroll
    for (int e = 0; e < 8; ++e) {
        if (se[e] <= y0) {
            float ex = fast_exp2(C1 * se[e]);
            P += ex;
            Pc = fmaf(ce[e], ex, Pc);
        } else {                                 // at most 31 of these per row
            unsigned idx = atomicAdd(&dcnt, 1u);
            dsS[idx] = se[e];
            dsC[idx] = ce[e];
        }
    }
#pragma unroll
    for (int off = 32; off > 0; off >>= 1) {
        P  += __shfl_xor(P,  off, 64);
        Pc += __shfl_xor(Pc, off, 64);
    }
    if (lane == 0) { pbuf[wv * 2] = P; pbuf[wv * 2 + 1] = Pc; }
    __syncthreads();
    float Pt = 0.f, Pct = 0.f;
#pragma unroll
    for (int w = 0; w < 16; ++w) { Pt += pbuf[w * 2]; Pct += pbuf[w * 2 + 1]; }
    const int nD = (int)dcnt;

    // ---- wave wv owns j = 2wv, 2wv+1 ----
    const float yj0 = yk_lds[2 * wv];
    const float yj1 = yk_lds[2 * wv + 1];
    float n0 = 0.f, d0 = 0.f, n1 = 0.f, d1 = 0.f;
    if (lane < nD) {
        float s = dsS[lane], c = dsC[lane];
        float e0 = fast_exp2(-C1 * fabsf(s - yj0));
        float e1 = fast_exp2(-C1 * fabsf(s - yj1));
        d0 = e0; n0 = c * e0;
        d1 = e1; n1 = c * e1;
    }
#pragma unroll
    for (int off = 32; off > 0; off >>= 1) {
        n0 += __shfl_xor(n0, off, 64); d0 += __shfl_xor(d0, off, 64);
        n1 += __shfl_xor(n1, off, 64); d1 += __shfl_xor(d1, off, 64);
    }
    if (lane == 0) {
        float e0 = fast_exp2(-C1 * yj0);
        float e1 = fast_exp2(-C1 * yj1);
        float* dst = out + (size_t)B * K_TOP + (size_t)row * K_TOP + 2 * wv;
        dst[0] = fmaf(Pct, e0, n0) / fmaf(Pt, e0, d0);
        dst[1] = fmaf(Pct, e1, n1) / fmaf(Pt, e1, d1);
    }
}

extern "C" void kernel_launch(void* const* d_in, const int* in_sizes, int n_in,
                              void* d_out, int out_size, void* d_ws, size_t ws_size,
                              hipStream_t stream) {
    const float* scores = (const float*)d_in[0];
    const int*   rc     = (const int*)d_in[1];
    const int R = in_sizes[1];          // 8192
    const int B = in_sizes[0] / R;      // 128
    float* out = (float*)d_out;

    hipLaunchKernelGGL(k_fused, dim3(B), dim3(1024), 0, stream, scores, rc, out, B);
}